// Round 1
// baseline (325.168 us; speedup 1.0000x reference)
//
#include <hip/hip_runtime.h>
#include <hip/hip_bf16.h>

// Problem constants (from reference): B=64, N=8192.
// Output: concat(feats_final (B,N,2), feats_sparse (B,N,2)) as float32.

#define BB 64
#define NN 8192
#define KWARM 64      // warm-up steps for the contraction-based parallel scan
#define SEG 256       // positions per block in scan kernel
#define CSEG 64       // positions per block in conv kernel

// ---------------------------------------------------------------------------
// Kernel 1: parallel continued-fraction scan + G_ii + mask -> feats_sparse
// The Mobius map x -> (z - a) - 1/x with Im z = 1 contracts errors by
// 1/|L|^2 <= 1 per step (typically ~0.2-0.3), so KWARM=64 steps from an
// arbitrary seed reproduce L_i / R_i to ~1e-12. Start clamped to the true
// boundary makes positions within KWARM of either end exact.
// ---------------------------------------------------------------------------
__global__ __launch_bounds__(256) void scan_feats_kernel(
    const float* __restrict__ v,
    const float* __restrict__ mask,
    float* __restrict__ fs)   // (B,N,2) feats_sparse
{
    __shared__ float sa[SEG + 2 * KWARM];
    const int b   = blockIdx.y;
    const int s0  = blockIdx.x * SEG;
    const int tid = threadIdx.x;

    // stage a[s0-K .. s0+SEG+K) (clamped; clamped values are never used)
    for (int idx = tid; idx < SEG + 2 * KWARM; idx += 256) {
        int g = s0 - KWARM + idx;
        g = min(max(g, 0), NN - 1);
        sa[idx] = v[b * NN + g] - 2.0f;
    }
    __syncthreads();

    const int i    = s0 + tid;
    const int iloc = KWARM + tid;

    // ---- left recursion: L_j = z - a_j - 1/L_{j-1}, seed at j0 ----
    int j0 = i - KWARM; if (j0 < 0) j0 = 0;
    int jl = j0 - (s0 - KWARM);
    float Lr = -sa[jl], Li = 1.0f;           // L_{j0} = z - a_{j0}
    for (int j = j0 + 1; j <= i; ++j) {
        ++jl;
        float d   = Lr * Lr + Li * Li;
        float inv = __builtin_amdgcn_rcpf(d);
        float nLr = -sa[jl] - Lr * inv;      // -(1/L) = (-Lr + i Li)/|L|^2
        float nLi = 1.0f + Li * inv;
        Lr = nLr; Li = nLi;
    }

    // ---- right recursion: R_j = z - a_j - 1/R_{j+1}, seed at j1 ----
    int j1 = i + KWARM; if (j1 > NN - 1) j1 = NN - 1;
    jl = j1 - (s0 - KWARM);
    float Rr = -sa[jl], Ri = 1.0f;           // R_{j1} = z - a_{j1}
    for (int j = j1 - 1; j >= i; --j) {
        --jl;
        float d   = Rr * Rr + Ri * Ri;
        float inv = __builtin_amdgcn_rcpf(d);
        float nRr = -sa[jl] - Rr * inv;
        float nRi = 1.0f + Ri * inv;
        Rr = nRr; Ri = nRi;
    }

    // G_ii = 1 / (L + R - (z - a_i))
    float Dr  = Lr + Rr + sa[iloc];
    float Di  = Li + Ri - 1.0f;
    float dd  = Dr * Dr + Di * Di;
    float inv = __builtin_amdgcn_rcpf(dd);
    float m   = mask[b * NN + i];
    float fr  =  Dr * inv * m;
    float fi  = -Di * inv * m;
    reinterpret_cast<float2*>(fs)[b * NN + i] = make_float2(fr, fi);
}

// ---------------------------------------------------------------------------
// Kernel 2: fused Conv1d(2->32)+ReLU -> Conv1d(32->32)+ReLU -> Conv1d(32->2)
// + mask select. One block = one batch row x CSEG positions. All
// intermediates live in LDS; conv2 is register-blocked 4 positions/thread
// with float4 LDS reads; w2 stored with row stride 161 (161%32==1) so the
// 4 distinct c_out groups per wave read distinct banks.
// ---------------------------------------------------------------------------
__global__ __launch_bounds__(256) void conv_stack_kernel(
    const float* __restrict__ fs,    // (B,N,2) feats_sparse
    const float* __restrict__ mask,
    const float* __restrict__ w1, const float* __restrict__ b1,
    const float* __restrict__ w2, const float* __restrict__ b2,
    const float* __restrict__ w3, const float* __restrict__ b3,
    float* __restrict__ outF)        // (B,N,2) feats_final
{
    __shared__ __align__(16) float xs[2][CSEG + 12];    // pos = s-6+p
    __shared__ __align__(16) float h1s[32][CSEG + 8];   // pos = s-4+p (stride 72)
    __shared__ __align__(16) float h2s[32][CSEG + 4];   // pos = s-2+p (stride 68)
    __shared__ float w1s[320], w3s[320];
    __shared__ float w2s[32 * 161];
    __shared__ float b1s[32], b2s[32], b3s[2];

    const int tid = threadIdx.x;
    const int b   = blockIdx.y;
    const int s   = blockIdx.x * CSEG;

    for (int idx = tid; idx < 320; idx += 256) { w1s[idx] = w1[idx]; w3s[idx] = w3[idx]; }
    for (int idx = tid; idx < 5120; idx += 256) {
        int co = idx / 160, r = idx - co * 160;
        w2s[co * 161 + r] = w2[idx];
    }
    if (tid < 32) { b1s[tid] = b1[tid]; b2s[tid] = b2[tid]; }
    if (tid < 2)  { b3s[tid] = b3[tid]; }

    // stage input (zero 'same' padding outside [0,N))
    for (int idx = tid; idx < 2 * (CSEG + 12); idx += 256) {
        int c = idx / (CSEG + 12), p = idx - c * (CSEG + 12);
        int g = s - 6 + p;
        float val = 0.0f;
        if (g >= 0 && g < NN) val = fs[(b * NN + g) * 2 + c];
        xs[c][p] = val;
    }
    __syncthreads();

    // conv1 -> relu (h1 halo positions outside [0,N) are zero, matching
    // the reference's zero padding of h1 into conv2)
    for (int idx = tid; idx < 32 * (CSEG + 8); idx += 256) {
        int co = idx / (CSEG + 8), p = idx - co * (CSEG + 8);
        int gpos = s - 4 + p;
        float acc = b1s[co];
        #pragma unroll
        for (int ci = 0; ci < 2; ++ci)
            #pragma unroll
            for (int kk = 0; kk < 5; ++kk)
                acc += w1s[(co * 2 + ci) * 5 + kk] * xs[ci][p + kk];
        float r = fmaxf(acc, 0.0f);
        h1s[co][p] = (gpos >= 0 && gpos < NN) ? r : 0.0f;
    }
    __syncthreads();

    // conv2 -> relu: 32 ch x 68 positions, 4 positions per (thread, idx)
    for (int idx = tid; idx < 32 * 17; idx += 256) {
        int co = idx / 17, g = idx - co * 17;
        int p0 = g * 4;
        float bias = b2s[co];
        float acc0 = bias, acc1 = bias, acc2 = bias, acc3 = bias;
        const float* wrow = &w2s[co * 161];
        #pragma unroll 4
        for (int ci = 0; ci < 32; ++ci) {
            float4 ha = *reinterpret_cast<const float4*>(&h1s[ci][p0]);
            float4 hb = *reinterpret_cast<const float4*>(&h1s[ci][p0 + 4]);
            float h[8] = {ha.x, ha.y, ha.z, ha.w, hb.x, hb.y, hb.z, hb.w};
            const float* wp = wrow + ci * 5;
            #pragma unroll
            for (int kk = 0; kk < 5; ++kk) {
                float w = wp[kk];
                acc0 += w * h[kk];
                acc1 += w * h[kk + 1];
                acc2 += w * h[kk + 2];
                acc3 += w * h[kk + 3];
            }
        }
        // zero h2 halo outside [0,N) (matches reference zero padding)
        int gp = s - 2 + p0;
        float4 o;
        o.x = (gp + 0 >= 0 && gp + 0 < NN) ? fmaxf(acc0, 0.0f) : 0.0f;
        o.y = (gp + 1 >= 0 && gp + 1 < NN) ? fmaxf(acc1, 0.0f) : 0.0f;
        o.z = (gp + 2 >= 0 && gp + 2 < NN) ? fmaxf(acc2, 0.0f) : 0.0f;
        o.w = (gp + 3 >= 0 && gp + 3 < NN) ? fmaxf(acc3, 0.0f) : 0.0f;
        *reinterpret_cast<float4*>(&h2s[co][p0]) = o;
    }
    __syncthreads();

    // conv3 + mask select + store feats_final
    for (int idx = tid; idx < 2 * CSEG; idx += 256) {
        int co = idx / CSEG, p = idx - co * CSEG;
        float acc = b3s[co];
        #pragma unroll 8
        for (int ci = 0; ci < 32; ++ci) {
            const float* wp = &w3s[(co * 32 + ci) * 5];
            #pragma unroll
            for (int kk = 0; kk < 5; ++kk)
                acc += wp[kk] * h2s[ci][p + kk];
        }
        int gpos = s + p;
        float m   = mask[b * NN + gpos];
        float fsv = xs[co][p + 6];
        outF[(b * NN + gpos) * 2 + co] = (m > 0.5f) ? fsv : acc;
    }
}

extern "C" void kernel_launch(void* const* d_in, const int* in_sizes, int n_in,
                              void* d_out, int out_size, void* d_ws, size_t ws_size,
                              hipStream_t stream) {
    const float* v    = (const float*)d_in[0];
    const float* mask = (const float*)d_in[1];
    const float* w1   = (const float*)d_in[2];
    const float* b1   = (const float*)d_in[3];
    const float* w2   = (const float*)d_in[4];
    const float* b2   = (const float*)d_in[5];
    const float* w3   = (const float*)d_in[6];
    const float* b3   = (const float*)d_in[7];

    float* outF = (float*)d_out;                  // feats_final (B,N,2)
    float* fs   = outF + (size_t)BB * NN * 2;     // feats_sparse (B,N,2)

    dim3 g1(NN / SEG, BB);
    scan_feats_kernel<<<g1, 256, 0, stream>>>(v, mask, fs);

    dim3 g2(NN / CSEG, BB);
    conv_stack_kernel<<<g2, 256, 0, stream>>>(fs, mask, w1, b1, w2, b2, w3, b3, outF);
}

// Round 2
// 154.114 us; speedup vs baseline: 2.1099x; 2.1099x over previous
//
#include <hip/hip_runtime.h>
#include <hip/hip_bf16.h>

// Problem constants (from reference): B=64, N=8192.
// Output: concat(feats_final (B,N,2), feats_sparse (B,N,2)) as float32.

#define BB 64
#define NN 8192
#define KWARM 64      // warm-up steps for the contraction-based parallel scan
#define SEG 256       // positions per block in scan kernel
#define CSEG 128      // positions per block in conv kernel

// ---------------------------------------------------------------------------
// Kernel 1: parallel continued-fraction scan + G_ii + mask -> feats_sparse
// Mobius map x -> (z - a) - 1/x with Im z = 1 contracts; KWARM=64 warm-up
// steps from a clamped seed reproduce L_i/R_i far below threshold.
// ---------------------------------------------------------------------------
__global__ __launch_bounds__(256) void scan_feats_kernel(
    const float* __restrict__ v,
    const float* __restrict__ mask,
    float* __restrict__ fs)   // (B,N,2) feats_sparse
{
    __shared__ float sa[SEG + 2 * KWARM];
    const int b   = blockIdx.y;
    const int s0  = blockIdx.x * SEG;
    const int tid = threadIdx.x;

    for (int idx = tid; idx < SEG + 2 * KWARM; idx += 256) {
        int g = s0 - KWARM + idx;
        g = min(max(g, 0), NN - 1);
        sa[idx] = v[b * NN + g] - 2.0f;
    }
    __syncthreads();

    const int i    = s0 + tid;
    const int iloc = KWARM + tid;

    int j0 = i - KWARM; if (j0 < 0) j0 = 0;
    int jl = j0 - (s0 - KWARM);
    float Lr = -sa[jl], Li = 1.0f;
    for (int j = j0 + 1; j <= i; ++j) {
        ++jl;
        float d   = Lr * Lr + Li * Li;
        float inv = __builtin_amdgcn_rcpf(d);
        float nLr = -sa[jl] - Lr * inv;
        float nLi = 1.0f + Li * inv;
        Lr = nLr; Li = nLi;
    }

    int j1 = i + KWARM; if (j1 > NN - 1) j1 = NN - 1;
    jl = j1 - (s0 - KWARM);
    float Rr = -sa[jl], Ri = 1.0f;
    for (int j = j1 - 1; j >= i; --j) {
        --jl;
        float d   = Rr * Rr + Ri * Ri;
        float inv = __builtin_amdgcn_rcpf(d);
        float nRr = -sa[jl] - Rr * inv;
        float nRi = 1.0f + Ri * inv;
        Rr = nRr; Ri = nRi;
    }

    float Dr  = Lr + Rr + sa[iloc];
    float Di  = Li + Ri - 1.0f;
    float dd  = Dr * Dr + Di * Di;
    float inv = __builtin_amdgcn_rcpf(dd);
    float m   = mask[b * NN + i];
    float fr  =  Dr * inv * m;
    float fi  = -Di * inv * m;
    reinterpret_cast<float2*>(fs)[b * NN + i] = make_float2(fr, fi);
}

// ---------------------------------------------------------------------------
// Kernel 2: fused conv stack, restructured for LDS-broadcast h reads and
// dense weight reads.
//   thread = (co = tid&31, posgroup pg = tid>>5); 16 positions per thread.
//   h1 reads: only 2 distinct addresses per wave -> LDS broadcast (free).
//   w2 re-chunked as w2c[sub(40)][co(32)][4] -> the 32 co-lanes of a wave
//   read 32 distinct 16B slots = dense delivery, no >4-way serialization.
//   Inner loop: 25 ds_read_b128 per 320 FMAs -> VALU-bound.
// ---------------------------------------------------------------------------
__global__ __launch_bounds__(256) void conv_stack_kernel(
    const float* __restrict__ fs,    // (B,N,2) feats_sparse
    const float* __restrict__ mask,
    const float* __restrict__ w1, const float* __restrict__ b1,
    const float* __restrict__ w2, const float* __restrict__ b2,
    const float* __restrict__ w3, const float* __restrict__ b3,
    float* __restrict__ outF)        // (B,N,2) feats_final
{
    __shared__ __align__(16) float xs[2][CSEG + 12];     // pos = s-6+p
    __shared__ __align__(16) float h1s[32][CSEG + 8];    // pos = s-4+p (stride 136)
    __shared__ __align__(16) float h2s[32][CSEG + 4];    // pos = s-2+p (stride 132)
    __shared__ __align__(16) float w2c[5120];            // [sub][co][4]
    __shared__ float w1s[320], w3s[320];
    __shared__ float b1s[32], b2s[32], b3s[2];

    const int tid = threadIdx.x;
    const int b   = blockIdx.y;
    const int s   = blockIdx.x * CSEG;

    // ---- stage weights ----
    for (int idx = tid; idx < 320; idx += 256) { w1s[idx] = w1[idx]; w3s[idx] = w3[idx]; }
    // w2c flat idx = sub*128 + co*4 + j  holds  w2[co*160 + sub*4 + j]
    for (int idx = tid; idx < 5120; idx += 256) {
        int j = idx & 3, co = (idx >> 2) & 31, sub = idx >> 7;
        w2c[idx] = w2[co * 160 + sub * 4 + j];
    }
    if (tid < 32) { b1s[tid] = b1[tid]; b2s[tid] = b2[tid]; }
    if (tid < 2)  { b3s[tid] = b3[tid]; }

    // ---- stage input (zero 'same' padding outside [0,N)) ----
    for (int idx = tid; idx < 2 * (CSEG + 12); idx += 256) {
        int c = idx / (CSEG + 12), p = idx - c * (CSEG + 12);
        int g = s - 6 + p;
        float val = 0.0f;
        if (g >= 0 && g < NN) val = fs[(b * NN + g) * 2 + c];
        xs[c][p] = val;
    }
    __syncthreads();

    // ---- conv1 -> relu (h1 halo outside [0,N) zeroed) ----
    for (int idx = tid; idx < 32 * (CSEG + 8); idx += 256) {
        int co = idx / (CSEG + 8), p = idx - co * (CSEG + 8);
        int gpos = s - 4 + p;
        float acc = b1s[co];
        #pragma unroll
        for (int ci = 0; ci < 2; ++ci)
            #pragma unroll
            for (int kk = 0; kk < 5; ++kk)
                acc += w1s[(co * 2 + ci) * 5 + kk] * xs[ci][p + kk];
        h1s[co][p] = (gpos >= 0 && gpos < NN) ? fmaxf(acc, 0.0f) : 0.0f;
    }
    __syncthreads();

    // ---- conv2 -> relu: main part, 16 positions per thread ----
    {
        const int co    = tid & 31;
        const int pg    = tid >> 5;       // 0..7
        const int pbase = pg * 16;        // h2 index base

        float acc[16];
        #pragma unroll
        for (int p = 0; p < 16; ++p) acc[p] = b2s[co];

        for (int c = 0; c < 8; ++c) {     // 4 input channels per chunk
            float w[20];
            #pragma unroll
            for (int q = 0; q < 5; ++q) {
                float4 t = *reinterpret_cast<const float4*>(&w2c[(5 * c + q) * 128 + co * 4]);
                w[q * 4 + 0] = t.x; w[q * 4 + 1] = t.y;
                w[q * 4 + 2] = t.z; w[q * 4 + 3] = t.w;
            }
            #pragma unroll
            for (int ci2 = 0; ci2 < 4; ++ci2) {
                const int ci = 4 * c + ci2;
                float hbuf[20];
                #pragma unroll
                for (int q = 0; q < 5; ++q) {
                    float4 t = *reinterpret_cast<const float4*>(&h1s[ci][pbase + 4 * q]);
                    hbuf[q * 4 + 0] = t.x; hbuf[q * 4 + 1] = t.y;
                    hbuf[q * 4 + 2] = t.z; hbuf[q * 4 + 3] = t.w;
                }
                #pragma unroll
                for (int kk = 0; kk < 5; ++kk) {
                    float wv = w[ci2 * 5 + kk];
                    #pragma unroll
                    for (int p = 0; p < 16; ++p)
                        acc[p] += wv * hbuf[p + kk];
                }
            }
        }
        // store h2 (zero outside [0,N))
        #pragma unroll
        for (int p = 0; p < 16; ++p) {
            int gp = s - 2 + pbase + p;
            h2s[co][pbase + p] = (gp >= 0 && gp < NN) ? fmaxf(acc[p], 0.0f) : 0.0f;
        }
    }
    // ---- conv2 tail: h2 positions q = 128..131 (conv3 halo), 128 threads ----
    if (tid < 128) {
        int co2 = tid & 31, q = CSEG + (tid >> 5);   // 128..131
        float a2 = b2s[co2];
        for (int ci = 0; ci < 32; ++ci) {
            #pragma unroll
            for (int kk = 0; kk < 5; ++kk) {
                int r = ci * 5 + kk;
                a2 += w2c[(r >> 2) * 128 + co2 * 4 + (r & 3)] * h1s[ci][q + kk];
            }
        }
        int gp = s - 2 + q;
        h2s[co2][q] = (gp >= 0 && gp < NN) ? fmaxf(a2, 0.0f) : 0.0f;
    }
    __syncthreads();

    // ---- conv3 + mask select + store feats_final ----
    {
        const int co = tid >> 7;          // 0..1
        const int p  = tid & 127;         // 0..127
        float acc = b3s[co];
        #pragma unroll 8
        for (int ci = 0; ci < 32; ++ci) {
            const float* wp = &w3s[(co * 32 + ci) * 5];
            #pragma unroll
            for (int kk = 0; kk < 5; ++kk)
                acc += wp[kk] * h2s[ci][p + kk];
        }
        int gpos = s + p;
        float m   = mask[b * NN + gpos];
        float fsv = xs[co][p + 6];
        outF[(b * NN + gpos) * 2 + co] = (m > 0.5f) ? fsv : acc;
    }
}

extern "C" void kernel_launch(void* const* d_in, const int* in_sizes, int n_in,
                              void* d_out, int out_size, void* d_ws, size_t ws_size,
                              hipStream_t stream) {
    const float* v    = (const float*)d_in[0];
    const float* mask = (const float*)d_in[1];
    const float* w1   = (const float*)d_in[2];
    const float* b1   = (const float*)d_in[3];
    const float* w2   = (const float*)d_in[4];
    const float* b2   = (const float*)d_in[5];
    const float* w3   = (const float*)d_in[6];
    const float* b3   = (const float*)d_in[7];

    float* outF = (float*)d_out;                  // feats_final (B,N,2)
    float* fs   = outF + (size_t)BB * NN * 2;     // feats_sparse (B,N,2)

    dim3 g1(NN / SEG, BB);
    scan_feats_kernel<<<g1, 256, 0, stream>>>(v, mask, fs);

    dim3 g2(NN / CSEG, BB);
    conv_stack_kernel<<<g2, 256, 0, stream>>>(fs, mask, w1, b1, w2, b2, w3, b3, outF);
}

// Round 4
// 68.356 us; speedup vs baseline: 4.7570x; 2.2546x over previous
//
#include <hip/hip_runtime.h>
#include <hip/hip_bf16.h>

// B=64, N=8192. Output: concat(feats_final (B,N,2), feats_sparse (B,N,2)) f32.

#define BB 64
#define NN 8192
#define KWARM 64      // warm-up steps for contraction-based parallel scan
#define SEG 256       // positions per block, scan kernel
#define CSEG 128      // output positions per block, conv kernel

using half8  = __attribute__((ext_vector_type(8))) _Float16;
using f32x16 = __attribute__((ext_vector_type(16))) float;

__device__ __forceinline__ half8 ld8(const ushort* p) {
    // two ds_read_b64 (8B-aligned); rows have 72B stride so b128 would misalign
    union { half8 v; unsigned long long q[2]; } u;
    u.q[0] = *reinterpret_cast<const unsigned long long*>(p);
    u.q[1] = *reinterpret_cast<const unsigned long long*>(p + 4);
    return u.v;
}
__device__ __forceinline__ ushort f2h(float x) {
    _Float16 h = (_Float16)x;              // v_cvt_f16_f32, RN
    return __builtin_bit_cast(unsigned short, h);
}

// ---------------------------------------------------------------------------
// Kernel 1: parallel continued-fraction scan + G_ii + mask -> feats_sparse
// ---------------------------------------------------------------------------
__global__ __launch_bounds__(256) void scan_feats_kernel(
    const float* __restrict__ v,
    const float* __restrict__ mask,
    float* __restrict__ fs)
{
    __shared__ float sa[SEG + 2 * KWARM];
    const int b   = blockIdx.y;
    const int s0  = blockIdx.x * SEG;
    const int tid = threadIdx.x;

    for (int idx = tid; idx < SEG + 2 * KWARM; idx += 256) {
        int g = s0 - KWARM + idx;
        g = min(max(g, 0), NN - 1);
        sa[idx] = v[b * NN + g] - 2.0f;
    }
    __syncthreads();

    const int i    = s0 + tid;
    const int iloc = KWARM + tid;

    int j0 = i - KWARM; if (j0 < 0) j0 = 0;
    int jl = j0 - (s0 - KWARM);
    float Lr = -sa[jl], Li = 1.0f;
    for (int j = j0 + 1; j <= i; ++j) {
        ++jl;
        float d   = Lr * Lr + Li * Li;
        float inv = __builtin_amdgcn_rcpf(d);
        float nLr = -sa[jl] - Lr * inv;
        float nLi = 1.0f + Li * inv;
        Lr = nLr; Li = nLi;
    }

    int j1 = i + KWARM; if (j1 > NN - 1) j1 = NN - 1;
    jl = j1 - (s0 - KWARM);
    float Rr = -sa[jl], Ri = 1.0f;
    for (int j = j1 - 1; j >= i; --j) {
        --jl;
        float d   = Rr * Rr + Ri * Ri;
        float inv = __builtin_amdgcn_rcpf(d);
        float nRr = -sa[jl] - Rr * inv;
        float nRi = 1.0f + Ri * inv;
        Rr = nRr; Ri = nRi;
    }

    float Dr  = Lr + Rr + sa[iloc];
    float Di  = Li + Ri - 1.0f;
    float dd  = Dr * Dr + Di * Di;
    float inv = __builtin_amdgcn_rcpf(dd);
    float m   = mask[b * NN + i];
    reinterpret_cast<float2*>(fs)[b * NN + i] =
        make_float2(Dr * inv * m, -Di * inv * m);
}

// ---------------------------------------------------------------------------
// Kernel 2: conv stack with MFMA conv2+conv3 (f16 in, f32 accum).
//   GEMM view, K reordered as k = kk*32 + ci:
//     A[m][k] = h1t[tile_base + m + kk][ci]   (transposed h1, f16, 72B rows)
//     B[k][n] = wt[n=co][k]
//   32x32x16 MFMA; A-frag: lane l -> m=l&31, k=8*(l>>5)+r; B-frag: n=l&31.
//   C/D: col(n)=lane&31, row(m)=(reg&3)+8*(reg>>2)+4*(lane>>5).
//   5 waves: conv2 tiles at local rows {0,32,64,96,100(overlap; identical
//   writes, benign)}; conv3 tiles 0..3 (N=2 of 32 used).
// ---------------------------------------------------------------------------
__global__ __launch_bounds__(320) void conv_stack_kernel(
    const float* __restrict__ fs,
    const float* __restrict__ mask,
    const float* __restrict__ w1, const float* __restrict__ b1,
    const float* __restrict__ w2, const float* __restrict__ b2,
    const float* __restrict__ w3, const float* __restrict__ b3,
    float* __restrict__ outF)
{
    __shared__ __align__(16) float  xs[2][CSEG + 12];   // x at pos s-6+p
    __shared__ __align__(16) float  ms[CSEG];
    __shared__ __align__(16) ushort h1t[136 * 36];      // [pos s-4+r][ci], f16
    __shared__ __align__(16) ushort wt2[32 * 160];      // [co][k=kk*32+ci]
    __shared__ __align__(16) ushort wt3[2 * 160];       // [co][k=kk*32+ci]
    __shared__ __align__(16) ushort h2t[132 * 36];      // [pos s-2+r][ci], f16
    __shared__ __align__(16) float  co3s[2][CSEG];
    __shared__ float w1s[320], b1s[32], b2s[32], b3s[2];

    const int tid = threadIdx.x;
    const int b   = blockIdx.y;
    const int s   = blockIdx.x * CSEG;

    // ---- stage ----
    w1s[tid < 320 ? tid : 0] = w1[tid < 320 ? tid : 0];
    if (tid < 32) { b1s[tid] = b1[tid]; b2s[tid] = b2[tid]; }
    if (tid < 2)  { b3s[tid] = b3[tid]; }
    if (tid < CSEG) ms[tid] = mask[b * NN + s + tid];
    { int co = tid / 160, k = tid % 160;                    // 320 elems of w3
      wt3[co * 160 + k] = f2h(w3[co * 160 + (k & 31) * 5 + (k >> 5)]); }
    for (int i = tid; i < 5120; i += 320) {
        int co = i / 160, k = i % 160;
        wt2[co * 160 + k] = f2h(w2[co * 160 + (k & 31) * 5 + (k >> 5)]);
    }
    for (int i = tid; i < CSEG + 12; i += 320) {
        int g = s - 6 + i;
        float2 val = make_float2(0.f, 0.f);
        if (g >= 0 && g < NN) val = reinterpret_cast<const float2*>(fs)[b * NN + g];
        xs[0][i] = val.x; xs[1][i] = val.y;
    }
    __syncthreads();

    // ---- conv1 (f32 VALU) -> h1t (f16, transposed, zero outside [0,N)) ----
    for (int t = tid; t < 136 * 16; t += 320) {
        int p = t >> 4, j = t & 15, co = 2 * j;
        float a0 = b1s[co], a1 = b1s[co + 1];
        #pragma unroll
        for (int ci = 0; ci < 2; ++ci)
            #pragma unroll
            for (int kk = 0; kk < 5; ++kk) {
                float xv = xs[ci][p + kk];
                a0 += w1s[(co * 2 + ci) * 5 + kk] * xv;
                a1 += w1s[(co * 2 + 2 + ci) * 5 + kk] * xv;
            }
        int gp = s - 4 + p;
        uint pk = (uint)f2h(fmaxf(a0, 0.f)) | ((uint)f2h(fmaxf(a1, 0.f)) << 16);
        *reinterpret_cast<uint*>(&h1t[p * 36 + co]) = (gp >= 0 && gp < NN) ? pk : 0u;
    }

    const int lane = tid & 63;
    const int wv   = tid >> 6;      // wave 0..4
    const int cn   = lane & 31;     // N-col (co) for B/C; M-row within tile for A
    const int kh   = lane >> 5;     // K-half

    half8 bw[10];
    #pragma unroll
    for (int t = 0; t < 10; ++t)
        bw[t] = ld8(&wt2[cn * 160 + 16 * t + 8 * kh]);
    __syncthreads();

    // ---- conv2 via MFMA -> h2t (f16, +bias, relu, zero outside [0,N)) ----
    const int tbl = (wv < 4) ? 32 * wv : 100;   // tile 4 overlaps tile 3
    {
        f32x16 acc = {};
        #pragma unroll
        for (int t = 0; t < 10; ++t) {
            int kk = t >> 1, ci0 = (t & 1) << 4;
            half8 av = ld8(&h1t[(tbl + cn + kk) * 36 + ci0 + 8 * kh]);
            acc = __builtin_amdgcn_mfma_f32_32x32x16_f16(av, bw[t], acc, 0, 0, 0);
        }
        float bias = b2s[cn];
        #pragma unroll
        for (int r = 0; r < 16; ++r) {
            int m   = (r & 3) + 8 * (r >> 2) + 4 * kh;
            int row = tbl + m;
            int gp  = s - 2 + row;
            float hv = fmaxf(acc[r] + bias, 0.f);
            h2t[row * 36 + cn] = (gp >= 0 && gp < NN) ? f2h(hv) : (ushort)0;
        }
    }
    __syncthreads();

    // ---- conv3 via MFMA (N=2 of 32 used) -> co3s ----
    {
        half8 bw3[10];
        #pragma unroll
        for (int t = 0; t < 10; ++t) {
            half8 z = {};
            bw3[t] = (cn < 2) ? ld8(&wt3[cn * 160 + 16 * t + 8 * kh]) : z;
        }
        if (wv < 4) {
            f32x16 a3 = {};
            #pragma unroll
            for (int t = 0; t < 10; ++t) {
                int kk = t >> 1, ci0 = (t & 1) << 4;
                half8 av = ld8(&h2t[(32 * wv + cn + kk) * 36 + ci0 + 8 * kh]);
                a3 = __builtin_amdgcn_mfma_f32_32x32x16_f16(av, bw3[t], a3, 0, 0, 0);
            }
            if (cn < 2) {
                float bias = b3s[cn];
                #pragma unroll
                for (int r = 0; r < 16; ++r) {
                    int m = (r & 3) + 8 * (r >> 2) + 4 * kh;
                    co3s[cn][32 * wv + m] = a3[r] + bias;
                }
            }
        }
    }
    __syncthreads();

    // ---- mask select + coalesced float2 store ----
    if (tid < CSEG) {
        float mk = ms[tid];
        float o0 = (mk > 0.5f) ? xs[0][tid + 6] : co3s[0][tid];
        float o1 = (mk > 0.5f) ? xs[1][tid + 6] : co3s[1][tid];
        reinterpret_cast<float2*>(outF)[b * NN + s + tid] = make_float2(o0, o1);
    }
}

extern "C" void kernel_launch(void* const* d_in, const int* in_sizes, int n_in,
                              void* d_out, int out_size, void* d_ws, size_t ws_size,
                              hipStream_t stream) {
    const float* v    = (const float*)d_in[0];
    const float* mask = (const float*)d_in[1];
    const float* w1   = (const float*)d_in[2];
    const float* b1   = (const float*)d_in[3];
    const float* w2   = (const float*)d_in[4];
    const float* b2   = (const float*)d_in[5];
    const float* w3   = (const float*)d_in[6];
    const float* b3   = (const float*)d_in[7];

    float* outF = (float*)d_out;                  // feats_final (B,N,2)
    float* fs   = outF + (size_t)BB * NN * 2;     // feats_sparse (B,N,2)

    dim3 g1(NN / SEG, BB);
    scan_feats_kernel<<<g1, 256, 0, stream>>>(v, mask, fs);

    dim3 g2(NN / CSEG, BB);
    conv_stack_kernel<<<g2, 320, 0, stream>>>(fs, mask, w1, b1, w2, b2, w3, b3, outF);
}

// Round 5
// 52.048 us; speedup vs baseline: 6.2475x; 1.3133x over previous
//
#include <hip/hip_runtime.h>
#include <hip/hip_bf16.h>

// B=64, N=8192. Output: concat(feats_final (B,N,2), feats_sparse (B,N,2)) f32.

#define BB 64
#define NN 8192
#define KWARM 64      // warm-up steps for contraction-based parallel scan
#define SSEG 1024     // positions per block, scan kernel
#define PCH 8         // positions emitted per chain
#define CSEG 128      // output positions per block, conv kernel

using half8  = __attribute__((ext_vector_type(8))) _Float16;
using f32x16 = __attribute__((ext_vector_type(16))) float;

__device__ __forceinline__ half8 ld8(const ushort* p) {
    union { half8 v; unsigned long long q[2]; } u;
    u.q[0] = *reinterpret_cast<const unsigned long long*>(p);
    u.q[1] = *reinterpret_cast<const unsigned long long*>(p + 4);
    return u.v;
}
__device__ __forceinline__ ushort f2h(float x) {
    _Float16 h = (_Float16)x;
    return __builtin_bit_cast(unsigned short, h);
}
// sa bank-swizzle: stride-8 chain reads would 16-way conflict; +(i>>5) spreads
#define SA(i) ((i) + ((i) >> 5))

// ---------------------------------------------------------------------------
// Kernel 1: chain-batched continued-fraction scan -> feats_sparse.
// Thread = one chain: warm >=64 steps from clamped seed (exact at true
// boundary), then emit PCH consecutive positions (1 step each).
// Also (block 0,0): pre-transpose conv weights to f16 in d_ws:
//   ws16[0..512)    wt1c[co][k=kk*2+ci], zero-padded k>=10
//   ws16[512..5632) wt2c[co][k=kk*32+ci]
//   ws16[5632..5952) wt3c[co][k=kk*32+ci]
// ---------------------------------------------------------------------------
__global__ __launch_bounds__(256) void scan_feats_kernel(
    const float* __restrict__ v,
    const float* __restrict__ mask,
    const float* __restrict__ w1,
    const float* __restrict__ w2,
    const float* __restrict__ w3,
    float* __restrict__ fs,
    ushort* __restrict__ ws16)
{
    __shared__ float sa[SA(SSEG + 2 * KWARM - 1) + 1];
    __shared__ float LsR[PCH][128], LsI[PCH][128];
    __shared__ float RsR[PCH][128], RsI[PCH][128];

    const int b   = blockIdx.y;
    const int s0  = blockIdx.x * SSEG;
    const int tid = threadIdx.x;

    for (int i = tid; i < SSEG + 2 * KWARM; i += 256) {
        int g = s0 - KWARM + i;
        g = min(max(g, 0), NN - 1);
        sa[SA(i)] = v[b * NN + g] - 2.0f;
    }
    __syncthreads();

    if (tid < 128) {
        // ---- L chain c = tid: emits local sa idx e0..e0+7 ----
        const int c  = tid;
        const int e0 = KWARM + c * PCH;
        int i0 = max(c * PCH, KWARM - s0);
        float Lr = -sa[SA(i0)], Li = 1.0f;
        if (i0 == e0) { LsR[0][c] = Lr; LsI[0][c] = Li; }
        for (int i = i0 + 1; i < e0 + PCH; ++i) {
            float d   = Lr * Lr + Li * Li;
            float inv = __builtin_amdgcn_rcpf(d);
            float nLr = -sa[SA(i)] - Lr * inv;
            float nLi = 1.0f + Li * inv;
            Lr = nLr; Li = nLi;
            if (i >= e0) { LsR[i - e0][c] = Lr; LsI[i - e0][c] = Li; }
        }
    } else {
        // ---- R chain c: emits local sa idx e1-7..e1 (descending) ----
        const int c  = tid - 128;
        const int e1 = KWARM + c * PCH + (PCH - 1);
        int i1 = min(c * PCH + (PCH - 1) + 2 * KWARM, (NN - 1) - s0 + KWARM);
        float Rr = -sa[SA(i1)], Ri = 1.0f;
        if (i1 == e1) { RsR[PCH - 1][c] = Rr; RsI[PCH - 1][c] = Ri; }
        for (int i = i1 - 1; i > e1 - PCH; --i) {
            float d   = Rr * Rr + Ri * Ri;
            float inv = __builtin_amdgcn_rcpf(d);
            float nRr = -sa[SA(i)] - Rr * inv;
            float nRi = 1.0f + Ri * inv;
            Rr = nRr; Ri = nRi;
            if (i <= e1) { RsR[i - e1 + PCH - 1][c] = Rr; RsI[i - e1 + PCH - 1][c] = Ri; }
        }
    }
    __syncthreads();

    // ---- combine + mask + store (4 positions/thread, coalesced) ----
    #pragma unroll
    for (int q = 0; q < 4; ++q) {
        int p = tid + 256 * q;
        int c = p >> 3, j = p & 7;
        float Lr = LsR[j][c], Li = LsI[j][c];
        float Rr = RsR[j][c], Ri = RsI[j][c];
        float a  = sa[SA(KWARM + p)];
        float Dr = Lr + Rr + a;
        float Di = Li + Ri - 1.0f;
        float inv = __builtin_amdgcn_rcpf(Dr * Dr + Di * Di);
        float m  = mask[b * NN + s0 + p];
        reinterpret_cast<float2*>(fs)[b * NN + s0 + p] =
            make_float2(Dr * inv * m, -Di * inv * m);
    }

    // ---- weight pre-transpose (one block; overlapped with other blocks) ----
    if (blockIdx.x == 0 && blockIdx.y == 0) {
        for (int i = tid; i < 512; i += 256) {
            int co = i >> 4, k = i & 15;
            ws16[i] = (k < 10) ? f2h(w1[co * 10 + (k & 1) * 5 + (k >> 1)]) : (ushort)0;
        }
        for (int i = tid; i < 5120; i += 256) {
            int co = i / 160, k = i % 160;
            ws16[512 + i] = f2h(w2[co * 160 + (k & 31) * 5 + (k >> 5)]);
        }
        for (int i = tid; i < 320; i += 256) {
            int co = i / 160, k = i % 160;
            ws16[5632 + i] = f2h(w3[co * 160 + (k & 31) * 5 + (k >> 5)]);
        }
    }
}

// ---------------------------------------------------------------------------
// Kernel 2: conv stack, all three convs via 32x32x16 f16 MFMA.
//   conv1: K=16 (k=kk*2+ci, zero-padded k>=10); A-row m = consecutive
//          f16-interleaved x pairs -> 4 uint LDS reads per fragment.
//   conv2: K=160 (k=kk*32+ci), A from transposed h1t (72B rows).
//   conv3: same GEMM, N=2 of 32 used.
//   A-frag: lane l -> m=l&31, k=8*(l>>5)+r. B-frag: n=l&31, same k.
//   C/D: col=lane&31, row=(r&3)+8*(r>>2)+4*(lane>>5).
// ---------------------------------------------------------------------------
__global__ __launch_bounds__(320) void conv_stack_kernel(
    const float* __restrict__ fs,
    const float* __restrict__ mask,
    const float* __restrict__ b1,
    const float* __restrict__ b2,
    const float* __restrict__ b3,
    const ushort* __restrict__ wsw,
    float* __restrict__ outF)
{
    __shared__ __align__(16) uint   xspu[CSEG + 12];   // f16 pair (x0,x1), pos s-6+i
    __shared__ __align__(16) ushort wt_all[5952];      // wt1c | wt2c | wt3c
    __shared__ __align__(16) ushort h1t[136 * 36];     // [pos s-4+r][ci]
    __shared__ __align__(16) ushort h2t[132 * 36];     // [pos s-2+r][ci]
    __shared__ __align__(16) float  co3s[2][CSEG];
    __shared__ float b1s[32], b2s[32], b3s[2];

    const int tid = threadIdx.x;
    const int b   = blockIdx.y;
    const int s   = blockIdx.x * CSEG;

    // ---- stage ----
    for (int i = tid; i < 2976; i += 320)
        *reinterpret_cast<uint*>(&wt_all[2 * i]) = reinterpret_cast<const uint*>(wsw)[i];
    if (tid < 32) { b1s[tid] = b1[tid]; b2s[tid] = b2[tid]; }
    if (tid < 2)  { b3s[tid] = b3[tid]; }
    for (int i = tid; i < CSEG + 12; i += 320) {
        int g = s - 6 + i;
        float2 val = make_float2(0.f, 0.f);
        if (g >= 0 && g < NN) val = reinterpret_cast<const float2*>(fs)[b * NN + g];
        xspu[i] = (uint)f2h(val.x) | ((uint)f2h(val.y) << 16);
    }
    __syncthreads();

    const int lane = tid & 63;
    const int wv   = tid >> 6;      // wave 0..4
    const int cn   = lane & 31;
    const int kh   = lane >> 5;

    // ---- conv1 via MFMA -> h1t (tiles {0,32,64,96,104}; overlap benign) ----
    {
        const int tb1 = (wv < 4) ? 32 * wv : 104;
        union { half8 v; uint u[4]; } A;
        int mi = tb1 + cn;
        A.u[0] = xspu[mi + 4 * kh];
        A.u[1] = kh ? 0u : xspu[mi + 1];
        A.u[2] = kh ? 0u : xspu[mi + 2];
        A.u[3] = kh ? 0u : xspu[mi + 3];
        half8 bw1 = ld8(&wt_all[cn * 16 + 8 * kh]);
        f32x16 a1 = {};
        a1 = __builtin_amdgcn_mfma_f32_32x32x16_f16(A.v, bw1, a1, 0, 0, 0);
        float bias = b1s[cn];
        #pragma unroll
        for (int r = 0; r < 16; ++r) {
            int m   = (r & 3) + 8 * (r >> 2) + 4 * kh;
            int row = tb1 + m;
            int gp  = s - 4 + row;
            h1t[row * 36 + cn] = (gp >= 0 && gp < NN) ? f2h(fmaxf(a1[r] + bias, 0.f))
                                                      : (ushort)0;
        }
    }
    // preload conv2 B-frags (wt2c already staged)
    const ushort* wt2c = wt_all + 512;
    half8 bw[10];
    #pragma unroll
    for (int t = 0; t < 10; ++t)
        bw[t] = ld8(&wt2c[cn * 160 + 16 * t + 8 * kh]);
    __syncthreads();

    // ---- conv2 via MFMA -> h2t (tiles {0,32,64,96,100}; overlap benign) ----
    {
        const int tb2 = (wv < 4) ? 32 * wv : 100;
        f32x16 acc = {};
        #pragma unroll
        for (int t = 0; t < 10; ++t) {
            int kk = t >> 1, ci0 = (t & 1) << 4;
            half8 av = ld8(&h1t[(tb2 + cn + kk) * 36 + ci0 + 8 * kh]);
            acc = __builtin_amdgcn_mfma_f32_32x32x16_f16(av, bw[t], acc, 0, 0, 0);
        }
        float bias = b2s[cn];
        #pragma unroll
        for (int r = 0; r < 16; ++r) {
            int m   = (r & 3) + 8 * (r >> 2) + 4 * kh;
            int row = tb2 + m;
            int gp  = s - 2 + row;
            h2t[row * 36 + cn] = (gp >= 0 && gp < NN) ? f2h(fmaxf(acc[r] + bias, 0.f))
                                                      : (ushort)0;
        }
    }
    __syncthreads();

    // ---- conv3 via MFMA (N=2 of 32 used) -> co3s ----
    {
        const ushort* wt3c = wt_all + 5632;
        half8 bw3[10];
        #pragma unroll
        for (int t = 0; t < 10; ++t) {
            half8 z = {};
            bw3[t] = (cn < 2) ? ld8(&wt3c[cn * 160 + 16 * t + 8 * kh]) : z;
        }
        if (wv < 4) {
            f32x16 a3 = {};
            #pragma unroll
            for (int t = 0; t < 10; ++t) {
                int kk = t >> 1, ci0 = (t & 1) << 4;
                half8 av = ld8(&h2t[(32 * wv + cn + kk) * 36 + ci0 + 8 * kh]);
                a3 = __builtin_amdgcn_mfma_f32_32x32x16_f16(av, bw3[t], a3, 0, 0, 0);
            }
            if (cn < 2) {
                float bias = b3s[cn];
                #pragma unroll
                for (int r = 0; r < 16; ++r) {
                    int m = (r & 3) + 8 * (r >> 2) + 4 * kh;
                    co3s[cn][32 * wv + m] = a3[r] + bias;
                }
            }
        }
    }
    __syncthreads();

    // ---- mask select + coalesced float2 store (fs/mask L2-hot) ----
    if (tid < CSEG) {
        int g = b * NN + s + tid;
        float mk  = mask[g];
        float2 fv = reinterpret_cast<const float2*>(fs)[g];
        float o0 = (mk > 0.5f) ? fv.x : co3s[0][tid];
        float o1 = (mk > 0.5f) ? fv.y : co3s[1][tid];
        reinterpret_cast<float2*>(outF)[g] = make_float2(o0, o1);
    }
}

extern "C" void kernel_launch(void* const* d_in, const int* in_sizes, int n_in,
                              void* d_out, int out_size, void* d_ws, size_t ws_size,
                              hipStream_t stream) {
    const float* v    = (const float*)d_in[0];
    const float* mask = (const float*)d_in[1];
    const float* w1   = (const float*)d_in[2];
    const float* b1   = (const float*)d_in[3];
    const float* w2   = (const float*)d_in[4];
    const float* b2   = (const float*)d_in[5];
    const float* w3   = (const float*)d_in[6];
    const float* b3   = (const float*)d_in[7];

    float*  outF = (float*)d_out;                  // feats_final (B,N,2)
    float*  fs   = outF + (size_t)BB * NN * 2;     // feats_sparse (B,N,2)
    ushort* ws16 = (ushort*)d_ws;                  // f16 transposed weights

    dim3 g1(NN / SSEG, BB);
    scan_feats_kernel<<<g1, 256, 0, stream>>>(v, mask, w1, w2, w3, fs, ws16);

    dim3 g2(NN / CSEG, BB);
    conv_stack_kernel<<<g2, 320, 0, stream>>>(fs, mask, b1, b2, b3, ws16, outF);
}

// Round 6
// 35.818 us; speedup vs baseline: 9.0783x; 1.4531x over previous
//
#include <hip/hip_runtime.h>
#include <hip/hip_bf16.h>

// B=64, N=8192. Output: concat(feats_final (B,N,2), feats_sparse (B,N,2)) f32.
// Single fused kernel: chain-scan (G_ii) + 3-layer conv stack via f16 MFMA.

#define BB 64
#define NN 8192
#define KWARM 64          // warm-up steps (contraction kills seed error)
#define TSEG 1024         // output positions per block
#define H 8               // xsp halo each side (conv needs 6)
#define PCH 4             // positions emitted per chain thread
#define NCH 260           // (TSEG+2H)/PCH chain threads
#define CHK 256           // conv chunk size
#define NT 512            // threads (8 waves)

using half8  = __attribute__((ext_vector_type(8))) _Float16;
using f32x16 = __attribute__((ext_vector_type(16))) float;

__device__ __forceinline__ half8 ld8(const ushort* p) {
    union { half8 v; unsigned long long q[2]; } u;
    u.q[0] = *reinterpret_cast<const unsigned long long*>(p);
    u.q[1] = *reinterpret_cast<const unsigned long long*>(p + 4);
    return u.v;
}
__device__ __forceinline__ ushort f2h(float x) {
    _Float16 h = (_Float16)x;
    return __builtin_bit_cast(unsigned short, h);
}
// sa swizzle: stride-4 chain access -> 32 distinct banks across a wave
#define SA(i) ((i) + ((i) >> 5))

// chain step: X <- (z - a_P) - 1/X, z = i
#define CST(RV, IV, P) { float dd_ = RV*RV + IV*IV;                        \
    float iv_ = __builtin_amdgcn_rcpf(dd_);                                \
    float nr_ = -sa[SA((P) - base)] - RV*iv_;                              \
    IV = 1.0f + IV*iv_; RV = nr_; }
// G = 1/(L + R - (z - a_P)), times mask
#define GCOMB(LRV, LIV, P, MM, GR, GI) { float av_ = sa[SA((P) - base)];   \
    float Dr_ = LRV + Rr + av_, Di_ = LIV + Ri - 1.0f;                     \
    float iv_ = __builtin_amdgcn_rcpf(Dr_*Dr_ + Di_*Di_);                  \
    GR = Dr_*iv_*(MM); GI = -Di_*iv_*(MM); }

__global__ __launch_bounds__(NT, 4) void fused_kernel(
    const float* __restrict__ v,  const float* __restrict__ mask,
    const float* __restrict__ w1, const float* __restrict__ b1,
    const float* __restrict__ w2, const float* __restrict__ b2,
    const float* __restrict__ w3, const float* __restrict__ b3,
    float* __restrict__ outF, float* __restrict__ fs)
{
    __shared__ __align__(16) ushort h1t[264 * 36];   // [row rel c-4][ci]; aliases sa
    __shared__ __align__(16) ushort h2t[260 * 36];   // [row rel c-2][ci]
    __shared__ __align__(16) ushort wt1c[512];       // [co][k=kk*2+ci], pad k>=10
    __shared__ __align__(16) ushort wt2c[32 * 160];  // [co][k=kk*32+ci]
    __shared__ __align__(16) ushort wt3c[2 * 160];
    __shared__ __align__(16) uint   xsp[TSEG + 2*H]; // f16 (x0,x1) at pos s-8+i
    __shared__ __align__(4) unsigned char mskb[TSEG];
    __shared__ float b1s[32], b2s[32], b3s[2];

    const int tid  = threadIdx.x;
    const int b    = blockIdx.y;
    const int s    = blockIdx.x * TSEG;
    const int base = s - H - KWARM;                  // sa[SA(p-base)] = v[p]-2

    float* sa = reinterpret_cast<float*>(h1t);       // phase-A alias (4816 B)

    // ---- stage v (clamped; clamped entries only feed discarded warm-up) ----
    for (int i = tid; i < TSEG + 2*H + 2*KWARM; i += NT) {
        int g = base + i; g = min(max(g, 0), NN - 1);
        sa[SA(i)] = v[b * NN + g] - 2.0f;
    }
    __syncthreads();

    // ---- phase A: chains (threads 0..259) || weight staging (320..511) ----
    if (tid < NCH) {
        const int e0 = s - H + PCH * tid;
        const int xb = PCH * tid;
        if (e0 >= 0 && e0 + PCH <= NN) {
            float4 mv = *reinterpret_cast<const float4*>(&mask[b * NN + e0]);
            // L chain: seed clamped (exact at true boundary)
            int j0 = max(e0 - KWARM, 0);
            float Lr = -sa[SA(j0 - base)], Li = 1.0f;
            for (int j = j0 + 1; j <= e0; ++j) CST(Lr, Li, j);
            float L0r = Lr, L0i = Li;
            CST(Lr, Li, e0 + 1); float L1r = Lr, L1i = Li;
            CST(Lr, Li, e0 + 2); float L2r = Lr, L2i = Li;
            CST(Lr, Li, e0 + 3); float L3r = Lr, L3i = Li;
            // R chain descending
            int j1 = min(e0 + 3 + KWARM, NN - 1);
            float Rr = -sa[SA(j1 - base)], Ri = 1.0f;
            for (int j = j1 - 1; j >= e0 + 3; --j) CST(Rr, Ri, j);
            float g0r,g0i,g1r,g1i,g2r,g2i,g3r,g3i;
            GCOMB(L3r, L3i, e0 + 3, mv.w, g3r, g3i);
            CST(Rr, Ri, e0 + 2); GCOMB(L2r, L2i, e0 + 2, mv.z, g2r, g2i);
            CST(Rr, Ri, e0 + 1); GCOMB(L1r, L1i, e0 + 1, mv.y, g1r, g1i);
            CST(Rr, Ri, e0 + 0); GCOMB(L0r, L0i, e0 + 0, mv.x, g0r, g0i);

            uint4 pk;
            pk.x = (uint)f2h(g0r) | ((uint)f2h(g0i) << 16);
            pk.y = (uint)f2h(g1r) | ((uint)f2h(g1i) << 16);
            pk.z = (uint)f2h(g2r) | ((uint)f2h(g2i) << 16);
            pk.w = (uint)f2h(g3r) | ((uint)f2h(g3i) << 16);
            *reinterpret_cast<uint4*>(&xsp[xb]) = pk;

            if (e0 >= s && e0 < s + TSEG) {          // own (non-halo) positions
                float4 oa = make_float4(g0r, g0i, g1r, g1i);
                float4 ob = make_float4(g2r, g2i, g3r, g3i);
                size_t off = ((size_t)b * NN + e0) * 2;
                *reinterpret_cast<float4*>(&fs[off])       = oa;
                *reinterpret_cast<float4*>(&fs[off + 4])   = ob;
                *reinterpret_cast<float4*>(&outF[off])     = oa;   // default: fs
                *reinterpret_cast<float4*>(&outF[off + 4]) = ob;
                uint mb = (mv.x > 0.5f ? 1u : 0u) | (mv.y > 0.5f ? 1u : 0u) << 8
                        | (mv.z > 0.5f ? 1u : 0u) << 16 | (mv.w > 0.5f ? 1u : 0u) << 24;
                *reinterpret_cast<uint*>(&mskb[e0 - s]) = mb;
            }
        } else {
            uint4 z = {0u, 0u, 0u, 0u};              // zero 'same' padding
            *reinterpret_cast<uint4*>(&xsp[xb]) = z;
        }
    } else if (tid >= 320) {
        const int t0 = tid - 320;                    // 192 staging threads
        for (int i = t0; i < 512; i += 192) {
            int co = i >> 4, k = i & 15;
            wt1c[i] = (k < 10) ? f2h(w1[co*10 + (k&1)*5 + (k>>1)]) : (ushort)0;
        }
        for (int i = t0; i < 5120; i += 192) {
            int co = i / 160, k = i % 160;
            wt2c[i] = f2h(w2[co*160 + (k&31)*5 + (k>>5)]);
        }
        for (int i = t0; i < 320; i += 192) {
            int co = i / 160, k = i % 160;
            wt3c[i] = f2h(w3[co*160 + (k&31)*5 + (k>>5)]);
        }
        if (t0 < 32) { b1s[t0] = b1[t0]; b2s[t0] = b2[t0]; if (t0 < 2) b3s[t0] = b3[t0]; }
    }
    __syncthreads();
    // sa (aliased with h1t) is dead from here on.

    const int lane = tid & 63;
    const int wv   = tid >> 6;        // 0..7
    const int cn   = lane & 31;
    const int kh   = lane >> 5;

    half8 bw[10];                     // conv2 B-frags, persistent
    #pragma unroll
    for (int t = 0; t < 10; ++t) bw[t] = ld8(&wt2c[cn*160 + 16*t + 8*kh]);

    for (int ch = 0; ch < 4; ++ch) {
        const int cr = ch * CHK;      // chunk base rel s

        // ---- conv1: 9 tiles (rows rel c-4: 0..263); wave0 also does tile 8
        {
            half8 bw1 = ld8(&wt1c[cn*16 + 8*kh]);
            #pragma unroll
            for (int pass = 0; pass < 2; ++pass) {
                int t = (pass == 0) ? wv : ((wv == 0) ? 8 : -1);
                if (t >= 0) {
                    int tb1 = (t < 8) ? 32*t : 232;
                    int x0  = cr + 2 + tb1 + cn;     // xsp idx: (c-s)+2+row+kk
                    union { half8 v8; uint u[4]; } A;
                    if (kh == 0) { A.u[0]=xsp[x0]; A.u[1]=xsp[x0+1];
                                   A.u[2]=xsp[x0+2]; A.u[3]=xsp[x0+3]; }
                    else         { A.u[0]=xsp[x0+4]; A.u[1]=0; A.u[2]=0; A.u[3]=0; }
                    f32x16 a1 = {};
                    a1 = __builtin_amdgcn_mfma_f32_32x32x16_f16(A.v8, bw1, a1, 0, 0, 0);
                    float bias = b1s[cn];
                    #pragma unroll
                    for (int r = 0; r < 16; ++r) {
                        int m = (r&3) + 8*(r>>2) + 4*kh;
                        int row = tb1 + m;
                        int gp  = s + cr - 4 + row;
                        h1t[row*36 + cn] = (gp >= 0 && gp < NN)
                            ? f2h(fmaxf(a1[r] + bias, 0.f)) : (ushort)0;
                    }
                }
            }
        }
        __syncthreads();

        // ---- conv2: 9 tiles (h2 rows rel c-2: 0..259); wave0 also tile 8
        {
            #pragma unroll
            for (int pass = 0; pass < 2; ++pass) {
                int t = (pass == 0) ? wv : ((wv == 0) ? 8 : -1);
                if (t >= 0) {
                    int tb2 = (t < 8) ? 32*t : 228;
                    f32x16 acc = {};
                    #pragma unroll
                    for (int q = 0; q < 10; ++q) {
                        int kk = q >> 1, ci0 = (q & 1) << 4;
                        half8 av = ld8(&h1t[(tb2 + cn + kk)*36 + ci0 + 8*kh]);
                        acc = __builtin_amdgcn_mfma_f32_32x32x16_f16(av, bw[q], acc, 0, 0, 0);
                    }
                    float bias = b2s[cn];
                    #pragma unroll
                    for (int r = 0; r < 16; ++r) {
                        int m = (r&3) + 8*(r>>2) + 4*kh;
                        int row = tb2 + m;
                        int gp  = s + cr - 2 + row;
                        h2t[row*36 + cn] = (gp >= 0 && gp < NN)
                            ? f2h(fmaxf(acc[r] + bias, 0.f)) : (ushort)0;
                    }
                }
            }
        }
        __syncthreads();

        // ---- conv3: 8 tiles; lanes cn<2 overwrite outF where mask==0 ----
        {
            half8 bw3[10];
            #pragma unroll
            for (int q = 0; q < 10; ++q) {
                half8 z = {};
                bw3[q] = (cn < 2) ? ld8(&wt3c[cn*160 + 16*q + 8*kh]) : z;
            }
            f32x16 a3 = {};
            #pragma unroll
            for (int q = 0; q < 10; ++q) {
                int kk = q >> 1, ci0 = (q & 1) << 4;
                half8 av = ld8(&h2t[(32*wv + cn + kk)*36 + ci0 + 8*kh]);
                a3 = __builtin_amdgcn_mfma_f32_32x32x16_f16(av, bw3[q], a3, 0, 0, 0);
            }
            if (cn < 2) {
                float bias = b3s[cn];
                #pragma unroll
                for (int r = 0; r < 16; ++r) {
                    int m = (r&3) + 8*(r>>2) + 4*kh;
                    int p = 32*wv + m;
                    if (!mskb[cr + p])
                        outF[((size_t)b*NN + s + cr + p)*2 + cn] = a3[r] + bias;
                }
            }
        }
        __syncthreads();
    }
}

extern "C" void kernel_launch(void* const* d_in, const int* in_sizes, int n_in,
                              void* d_out, int out_size, void* d_ws, size_t ws_size,
                              hipStream_t stream) {
    const float* v    = (const float*)d_in[0];
    const float* mask = (const float*)d_in[1];
    const float* w1   = (const float*)d_in[2];
    const float* b1   = (const float*)d_in[3];
    const float* w2   = (const float*)d_in[4];
    const float* b2   = (const float*)d_in[5];
    const float* w3   = (const float*)d_in[6];
    const float* b3   = (const float*)d_in[7];

    float* outF = (float*)d_out;                  // feats_final (B,N,2)
    float* fs   = outF + (size_t)BB * NN * 2;     // feats_sparse (B,N,2)

    dim3 g(NN / TSEG, BB);                        // 8 x 64 = 512 blocks
    fused_kernel<<<g, NT, 0, stream>>>(v, mask, w1, b1, w2, b2, w3, b3, outF, fs);
}

// Round 7
// 34.102 us; speedup vs baseline: 9.5352x; 1.0503x over previous
//
#include <hip/hip_runtime.h>
#include <hip/hip_bf16.h>

// B=64, N=8192. Output: concat(feats_final (B,N,2), feats_sparse (B,N,2)) f32.
// Single fused kernel: chain-scan (G_ii) + 3-layer conv stack via f16 MFMA.

#define BB 64
#define NN 8192
#define KWARM 64          // warm-up steps (contraction kills seed error)
#define TSEG 1024         // output positions per block
#define H 8               // xsp halo each side (conv needs 6)
#define PCH 4             // positions emitted per chain thread
#define NCH 260           // (TSEG+2H)/PCH chain threads
#define CHK 256           // conv chunk size
#define NT 512            // threads (8 waves)

using half8  = __attribute__((ext_vector_type(8))) _Float16;
using f32x16 = __attribute__((ext_vector_type(16))) float;
using f32x4  = __attribute__((ext_vector_type(4))) float;

__device__ __forceinline__ half8 ld8(const ushort* p) {
    union { half8 v; unsigned long long q[2]; } u;
    u.q[0] = *reinterpret_cast<const unsigned long long*>(p);
    u.q[1] = *reinterpret_cast<const unsigned long long*>(p + 4);
    return u.v;
}
__device__ __forceinline__ ushort f2h(float x) {
    _Float16 h = (_Float16)x;
    return __builtin_bit_cast(unsigned short, h);
}

// chain step with explicit a-value: X <- (z - a) - 1/X, z = i
#define CSTV(RV, IV, AV) { float dd_ = RV*RV + IV*IV;                      \
    float iv_ = __builtin_amdgcn_rcpf(dd_);                                \
    float nr_ = -(AV) - RV*iv_;                                            \
    IV = 1.0f + IV*iv_; RV = nr_; }
// G = 1/(L + R - (z - a)), times mask
#define GC(LRV, LIV, RRV, RIV, AV, MM, GR, GI) {                           \
    float Dr_ = LRV + RRV + (AV), Di_ = LIV + RIV - 1.0f;                  \
    float iv_ = __builtin_amdgcn_rcpf(Dr_*Dr_ + Di_*Di_);                  \
    GR = Dr_*iv_*(MM); GI = -Di_*iv_*(MM); }

__global__ __launch_bounds__(NT, 4) void fused_kernel(
    const float* __restrict__ v,  const float* __restrict__ mask,
    const float* __restrict__ w1, const float* __restrict__ b1,
    const float* __restrict__ w2, const float* __restrict__ b2,
    const float* __restrict__ w3, const float* __restrict__ b3,
    float* __restrict__ outF, float* __restrict__ fs)
{
    __shared__ __align__(16) ushort h1t[264 * 36];   // [row rel c-4][ci]; aliases sa
    __shared__ __align__(16) ushort h2t[260 * 36];   // [row rel c-2][ci]
    __shared__ __align__(16) ushort wt1c[512];       // [co][k=kk*2+ci], pad k>=10
    __shared__ __align__(16) ushort wt2c[32 * 160];  // [co][k=kk*32+ci]
    __shared__ __align__(16) ushort wt3c[2 * 160];
    __shared__ __align__(16) uint   xsp[TSEG + 2*H]; // f16 (x0,x1) at pos s-8+i
    __shared__ __align__(4) unsigned char mskb[TSEG];
    __shared__ float b1s[32], b2s[32], b3s[2];

    const int tid  = threadIdx.x;
    const int b    = blockIdx.y;
    const int s    = blockIdx.x * TSEG;
    const int base = s - H - KWARM;                  // sa[p-base] = v[p]-2

    float* sa = reinterpret_cast<float*>(h1t);       // phase-A alias (4672 B)

    // ---- stage v (clamped; clamped entries only feed discarded warm-up) ----
    for (int i = tid; i < TSEG + 2*H + 2*KWARM; i += NT) {
        int g = base + i; g = min(max(g, 0), NN - 1);
        sa[i] = v[b * NN + g] - 2.0f;
    }
    __syncthreads();

    // ---- phase A: chains (threads 0..259) || weight staging (320..511) ----
    if (tid < NCH) {
        const int e0 = s - H + PCH * tid;
        if (e0 >= 0 && e0 + PCH <= NN) {
            float4 mv = *reinterpret_cast<const float4*>(&mask[b * NN + e0]);
            float Lr, Li, Rr, Ri;
            const bool fast = (e0 - KWARM >= 0) && (e0 + 3 + KWARM <= NN - 1);
            if (fast) {
                // interleaved L (ascending) + R (descending) warm-up,
                // float4 LDS reads, two independent rcp chains (ILP=2)
                const int i0 = e0 - KWARM - base;        // multiple of 4
                const int i1 = i0 + 131;
                const float4* s4 = reinterpret_cast<const float4*>(sa);
                float4 cL = s4[i0 >> 2];
                float4 cR = s4[(i1 - 3) >> 2];
                Lr = -cL.x; Li = 1.0f; Rr = -cR.w; Ri = 1.0f;
                CSTV(Lr, Li, cL.y); CSTV(Rr, Ri, cR.z);
                CSTV(Lr, Li, cL.z); CSTV(Rr, Ri, cR.y);
                CSTV(Lr, Li, cL.w); CSTV(Rr, Ri, cR.x);
                for (int g = 1; g <= 15; ++g) {
                    float4 nL = s4[(i0 + 4 * g) >> 2];
                    float4 nR = s4[(i1 - 3 - 4 * g) >> 2];
                    CSTV(Lr, Li, nL.x); CSTV(Rr, Ri, nR.w);
                    CSTV(Lr, Li, nL.y); CSTV(Rr, Ri, nR.z);
                    CSTV(Lr, Li, nL.z); CSTV(Rr, Ri, nR.y);
                    CSTV(Lr, Li, nL.w); CSTV(Rr, Ri, nR.x);
                }
                CSTV(Lr, Li, sa[i0 + 64]);   // L now at e0
                CSTV(Rr, Ri, sa[i0 + 67]);   // R now at e0+3
            } else {
                int j0 = max(e0 - KWARM, 0);
                Lr = -sa[j0 - base]; Li = 1.0f;
                for (int j = j0 + 1; j <= e0; ++j) CSTV(Lr, Li, sa[j - base]);
                int j1 = min(e0 + 3 + KWARM, NN - 1);
                Rr = -sa[j1 - base]; Ri = 1.0f;
                for (int j = j1 - 1; j >= e0 + 3; --j) CSTV(Rr, Ri, sa[j - base]);
            }
            // emit tail
            float a0v = sa[e0 - base],     a1v = sa[e0 + 1 - base];
            float a2v = sa[e0 + 2 - base], a3v = sa[e0 + 3 - base];
            float L0r = Lr, L0i = Li;
            CSTV(Lr, Li, a1v); float L1r = Lr, L1i = Li;
            CSTV(Lr, Li, a2v); float L2r = Lr, L2i = Li;
            CSTV(Lr, Li, a3v); float L3r = Lr, L3i = Li;
            float g0r,g0i,g1r,g1i,g2r,g2i,g3r,g3i;
            GC(L3r, L3i, Rr, Ri, a3v, mv.w, g3r, g3i);
            CSTV(Rr, Ri, a2v); GC(L2r, L2i, Rr, Ri, a2v, mv.z, g2r, g2i);
            CSTV(Rr, Ri, a1v); GC(L1r, L1i, Rr, Ri, a1v, mv.y, g1r, g1i);
            CSTV(Rr, Ri, a0v); GC(L0r, L0i, Rr, Ri, a0v, mv.x, g0r, g0i);

            uint4 pk;
            pk.x = (uint)f2h(g0r) | ((uint)f2h(g0i) << 16);
            pk.y = (uint)f2h(g1r) | ((uint)f2h(g1i) << 16);
            pk.z = (uint)f2h(g2r) | ((uint)f2h(g2i) << 16);
            pk.w = (uint)f2h(g3r) | ((uint)f2h(g3i) << 16);
            *reinterpret_cast<uint4*>(&xsp[PCH * tid]) = pk;

            if (e0 >= s && e0 < s + TSEG) {          // own (non-halo) positions
                float4 oa = make_float4(g0r, g0i, g1r, g1i);
                float4 ob = make_float4(g2r, g2i, g3r, g3i);
                size_t off = ((size_t)b * NN + e0) * 2;
                *reinterpret_cast<float4*>(&fs[off])       = oa;
                *reinterpret_cast<float4*>(&fs[off + 4])   = ob;
                *reinterpret_cast<float4*>(&outF[off])     = oa;   // default: fs
                *reinterpret_cast<float4*>(&outF[off + 4]) = ob;
                uint mb = (mv.x > 0.5f ? 1u : 0u) | (mv.y > 0.5f ? 1u : 0u) << 8
                        | (mv.z > 0.5f ? 1u : 0u) << 16 | (mv.w > 0.5f ? 1u : 0u) << 24;
                *reinterpret_cast<uint*>(&mskb[e0 - s]) = mb;
            }
        } else {
            uint4 z = {0u, 0u, 0u, 0u};              // zero 'same' padding
            *reinterpret_cast<uint4*>(&xsp[PCH * tid]) = z;
        }
    } else if (tid >= 320) {
        const int t0 = tid - 320;                    // 192 staging threads
        for (int i = t0; i < 512; i += 192) {
            int co = i >> 4, k = i & 15;
            wt1c[i] = (k < 10) ? f2h(w1[co*10 + (k&1)*5 + (k>>1)]) : (ushort)0;
        }
        for (int i = t0; i < 5120; i += 192) {
            int co = i / 160, k = i % 160;
            wt2c[i] = f2h(w2[co*160 + (k&31)*5 + (k>>5)]);
        }
        for (int i = t0; i < 320; i += 192) {
            int co = i / 160, k = i % 160;
            wt3c[i] = f2h(w3[co*160 + (k&31)*5 + (k>>5)]);
        }
        if (t0 < 32) { b1s[t0] = b1[t0]; b2s[t0] = b2[t0]; if (t0 < 2) b3s[t0] = b3[t0]; }
    }
    __syncthreads();
    // sa (aliased with h1t) is dead from here on.

    const int lane = tid & 63;
    const int wv   = tid >> 6;        // 0..7
    const int cn   = lane & 31;
    const int kh   = lane >> 5;
    const int ml   = lane & 15;       // conv3 16x16: A-row / C-col
    const int kg   = lane >> 4;       // conv3 16x16: k-group 0..3

    // persistent B-fragments (loop-invariant: hoisted out of chunk loop)
    half8 bw1 = ld8(&wt1c[cn * 16 + 8 * kh]);
    half8 bw[10];
    #pragma unroll
    for (int t = 0; t < 10; ++t) bw[t] = ld8(&wt2c[cn*160 + 16*t + 8*kh]);
    half8 bw3[5];
    {
        int co_b = (ml < 2) ? ml : 0;
        #pragma unroll
        for (int q = 0; q < 5; ++q)
            bw3[q] = ld8(&wt3c[co_b*160 + q*32 + kg*8]);
    }

    for (int ch = 0; ch < 4; ++ch) {
        const int cr = ch * CHK;      // chunk base rel s

        // ---- conv1: 9 tiles (rows rel c-4: 0..263); wave0 also does tile 8
        {
            #pragma unroll
            for (int pass = 0; pass < 2; ++pass) {
                int t = (pass == 0) ? wv : ((wv == 0) ? 8 : -1);
                if (t >= 0) {
                    int tb1 = (t < 8) ? 32*t : 232;
                    int x0  = cr + 2 + tb1 + cn;     // xsp idx: (c-s)+2+row+kk
                    union { half8 v8; uint u[4]; } A;
                    if (kh == 0) { A.u[0]=xsp[x0]; A.u[1]=xsp[x0+1];
                                   A.u[2]=xsp[x0+2]; A.u[3]=xsp[x0+3]; }
                    else         { A.u[0]=xsp[x0+4]; A.u[1]=0; A.u[2]=0; A.u[3]=0; }
                    f32x16 a1 = {};
                    a1 = __builtin_amdgcn_mfma_f32_32x32x16_f16(A.v8, bw1, a1, 0, 0, 0);
                    float bias = b1s[cn];
                    #pragma unroll
                    for (int r = 0; r < 16; ++r) {
                        int m = (r&3) + 8*(r>>2) + 4*kh;
                        int row = tb1 + m;
                        int gp  = s + cr - 4 + row;
                        h1t[row*36 + cn] = (gp >= 0 && gp < NN)
                            ? f2h(fmaxf(a1[r] + bias, 0.f)) : (ushort)0;
                    }
                }
            }
        }
        __syncthreads();

        // ---- conv2: 9 tiles; two independent 5-MFMA chains (latency /2) ----
        {
            #pragma unroll
            for (int pass = 0; pass < 2; ++pass) {
                int t = (pass == 0) ? wv : ((wv == 0) ? 8 : -1);
                if (t >= 0) {
                    int tb2 = (t < 8) ? 32*t : 228;
                    f32x16 aca = {}, acb = {};
                    #pragma unroll
                    for (int j = 0; j < 5; ++j) {
                        const ushort* rp = &h1t[(tb2 + cn + j)*36 + 8*kh];
                        aca = __builtin_amdgcn_mfma_f32_32x32x16_f16(ld8(rp),      bw[2*j],   aca, 0, 0, 0);
                        acb = __builtin_amdgcn_mfma_f32_32x32x16_f16(ld8(rp + 16), bw[2*j+1], acb, 0, 0, 0);
                    }
                    f32x16 acc = aca + acb;
                    float bias = b2s[cn];
                    #pragma unroll
                    for (int r = 0; r < 16; ++r) {
                        int m = (r&3) + 8*(r>>2) + 4*kh;
                        int row = tb2 + m;
                        int gp  = s + cr - 2 + row;
                        h2t[row*36 + cn] = (gp >= 0 && gp < NN)
                            ? f2h(fmaxf(acc[r] + bias, 0.f)) : (ushort)0;
                    }
                }
            }
        }
        __syncthreads();

        // ---- conv3 via 16x16x32 MFMA (N=2 of 16); 2 tiles/wave ----
        {
            #pragma unroll
            for (int t3i = 0; t3i < 2; ++t3i) {
                int rb = 16 * (2*wv + t3i);          // h2t row base
                f32x4 a3 = {};
                #pragma unroll
                for (int q = 0; q < 5; ++q) {
                    half8 av = ld8(&h2t[(rb + ml + q)*36 + kg*8]);
                    a3 = __builtin_amdgcn_mfma_f32_16x16x32_f16(av, bw3[q], a3, 0, 0, 0);
                }
                if (ml < 2) {
                    float bias = b3s[ml];
                    #pragma unroll
                    for (int r = 0; r < 4; ++r) {
                        int p = cr + rb + kg*4 + r;  // rel s
                        if (!mskb[p])
                            outF[((size_t)b*NN + s + p)*2 + ml] = a3[r] + bias;
                    }
                }
            }
        }
        // no barrier needed here: next conv1's post-barrier orders h1t/h2t reuse
    }
}

extern "C" void kernel_launch(void* const* d_in, const int* in_sizes, int n_in,
                              void* d_out, int out_size, void* d_ws, size_t ws_size,
                              hipStream_t stream) {
    const float* v    = (const float*)d_in[0];
    const float* mask = (const float*)d_in[1];
    const float* w1   = (const float*)d_in[2];
    const float* b1   = (const float*)d_in[3];
    const float* w2   = (const float*)d_in[4];
    const float* b2   = (const float*)d_in[5];
    const float* w3   = (const float*)d_in[6];
    const float* b3   = (const float*)d_in[7];

    float* outF = (float*)d_out;                  // feats_final (B,N,2)
    float* fs   = outF + (size_t)BB * NN * 2;     // feats_sparse (B,N,2)

    dim3 g(NN / TSEG, BB);                        // 8 x 64 = 512 blocks
    fused_kernel<<<g, NT, 0, stream>>>(v, mask, w1, b1, w2, b2, w3, b3, outF, fs);
}

// Round 8
// 33.955 us; speedup vs baseline: 9.5765x; 1.0043x over previous
//
#include <hip/hip_runtime.h>
#include <hip/hip_bf16.h>

// B=64, N=8192. Output: concat(feats_final (B,N,2), feats_sparse (B,N,2)) f32.
// Single fused kernel: chain-scan (G_ii) + 3-layer conv stack via f16 MFMA.
// h-tiles: [row][32ci] with 40-ushort (80 B) stride -> bank-group of
// (row, 16B-quarter q) = (5*row+q) mod 8, bijective in row mod 8 => all
// fragment ds_read_b128 are conflict-free at the 8-cyc wave64 minimum.

#define BB 64
#define NN 8192
#define KWARM 64          // warm-up steps (contraction kills seed error)
#define TSEG 1024         // output positions per block
#define H 8               // xsp halo each side (conv needs 6)
#define PCH 4             // positions emitted per chain thread
#define NCH 260           // (TSEG+2H)/PCH chain threads
#define CHK 256           // conv chunk size
#define NT 512            // threads (8 waves)
#define HST 40            // h-tile row stride in ushorts (80 B)

using half8  = __attribute__((ext_vector_type(8))) _Float16;
using f32x16 = __attribute__((ext_vector_type(16))) float;
using f32x4  = __attribute__((ext_vector_type(4))) float;

__device__ __forceinline__ half8 ld16(const ushort* p) {   // one ds_read_b128
    return *reinterpret_cast<const half8*>(p);
}
__device__ __forceinline__ half8 ld8(const ushort* p) {    // two ds_read_b64
    union { half8 v; unsigned long long q[2]; } u;
    u.q[0] = *reinterpret_cast<const unsigned long long*>(p);
    u.q[1] = *reinterpret_cast<const unsigned long long*>(p + 4);
    return u.v;
}
__device__ __forceinline__ ushort f2h(float x) {
    _Float16 h = (_Float16)x;
    return __builtin_bit_cast(unsigned short, h);
}

// chain step with explicit a-value: X <- (z - a) - 1/X, z = i
#define CSTV(RV, IV, AV) { float dd_ = RV*RV + IV*IV;                      \
    float iv_ = __builtin_amdgcn_rcpf(dd_);                                \
    float nr_ = -(AV) - RV*iv_;                                            \
    IV = 1.0f + IV*iv_; RV = nr_; }
// G = 1/(L + R - (z - a)), times mask
#define GC(LRV, LIV, RRV, RIV, AV, MM, GR, GI) {                           \
    float Dr_ = LRV + RRV + (AV), Di_ = LIV + RIV - 1.0f;                  \
    float iv_ = __builtin_amdgcn_rcpf(Dr_*Dr_ + Di_*Di_);                  \
    GR = Dr_*iv_*(MM); GI = -Di_*iv_*(MM); }

__global__ __launch_bounds__(NT, 4) void fused_kernel(
    const float* __restrict__ v,  const float* __restrict__ mask,
    const float* __restrict__ w1, const float* __restrict__ b1,
    const float* __restrict__ w2, const float* __restrict__ b2,
    const float* __restrict__ w3, const float* __restrict__ b3,
    float* __restrict__ outF, float* __restrict__ fs)
{
    __shared__ __align__(16) ushort h1t[264 * HST];  // [row rel c-4][ci]; aliases sa
    __shared__ __align__(16) ushort h2t[260 * HST];  // [row rel c-2][ci]
    __shared__ __align__(16) ushort wt1c[512];       // [co][k=kk*2+ci], pad k>=10
    __shared__ __align__(16) ushort wt2c[32 * 160];  // [co][k=kk*32+ci]
    __shared__ __align__(16) ushort wt3c[2 * 160];
    __shared__ __align__(16) uint   xsp[TSEG + 2*H]; // f16 (x0,x1) at pos s-8+i
    __shared__ __align__(4) unsigned char mskb[TSEG];
    __shared__ float b1s[32], b2s[32], b3s[2];

    const int tid  = threadIdx.x;
    const int b    = blockIdx.y;
    const int s    = blockIdx.x * TSEG;
    const int base = s - H - KWARM;                  // sa[p-base] = v[p]-2

    float* sa = reinterpret_cast<float*>(h1t);       // phase-A alias (4672 B)

    // ---- stage v (clamped; clamped entries only feed discarded warm-up) ----
    for (int i = tid; i < TSEG + 2*H + 2*KWARM; i += NT) {
        int g = base + i; g = min(max(g, 0), NN - 1);
        sa[i] = v[b * NN + g] - 2.0f;
    }
    __syncthreads();

    // ---- phase A: chains (threads 0..259) || weight staging (320..511) ----
    if (tid < NCH) {
        const int e0 = s - H + PCH * tid;
        if (e0 >= 0 && e0 + PCH <= NN) {
            float4 mv = *reinterpret_cast<const float4*>(&mask[b * NN + e0]);
            float Lr, Li, Rr, Ri;
            const bool fast = (e0 - KWARM >= 0) && (e0 + 3 + KWARM <= NN - 1);
            if (fast) {
                // interleaved L (ascending) + R (descending) warm-up,
                // float4 LDS reads, two independent rcp chains (ILP=2)
                const int i0 = e0 - KWARM - base;        // multiple of 4
                const int i1 = i0 + 131;
                const float4* s4 = reinterpret_cast<const float4*>(sa);
                float4 cL = s4[i0 >> 2];
                float4 cR = s4[(i1 - 3) >> 2];
                Lr = -cL.x; Li = 1.0f; Rr = -cR.w; Ri = 1.0f;
                CSTV(Lr, Li, cL.y); CSTV(Rr, Ri, cR.z);
                CSTV(Lr, Li, cL.z); CSTV(Rr, Ri, cR.y);
                CSTV(Lr, Li, cL.w); CSTV(Rr, Ri, cR.x);
                for (int g = 1; g <= 15; ++g) {
                    float4 nL = s4[(i0 + 4 * g) >> 2];
                    float4 nR = s4[(i1 - 3 - 4 * g) >> 2];
                    CSTV(Lr, Li, nL.x); CSTV(Rr, Ri, nR.w);
                    CSTV(Lr, Li, nL.y); CSTV(Rr, Ri, nR.z);
                    CSTV(Lr, Li, nL.z); CSTV(Rr, Ri, nR.y);
                    CSTV(Lr, Li, nL.w); CSTV(Rr, Ri, nR.x);
                }
                CSTV(Lr, Li, sa[i0 + 64]);   // L now at e0
                CSTV(Rr, Ri, sa[i0 + 67]);   // R now at e0+3
            } else {
                int j0 = max(e0 - KWARM, 0);
                Lr = -sa[j0 - base]; Li = 1.0f;
                for (int j = j0 + 1; j <= e0; ++j) CSTV(Lr, Li, sa[j - base]);
                int j1 = min(e0 + 3 + KWARM, NN - 1);
                Rr = -sa[j1 - base]; Ri = 1.0f;
                for (int j = j1 - 1; j >= e0 + 3; --j) CSTV(Rr, Ri, sa[j - base]);
            }
            // emit tail
            float a0v = sa[e0 - base],     a1v = sa[e0 + 1 - base];
            float a2v = sa[e0 + 2 - base], a3v = sa[e0 + 3 - base];
            float L0r = Lr, L0i = Li;
            CSTV(Lr, Li, a1v); float L1r = Lr, L1i = Li;
            CSTV(Lr, Li, a2v); float L2r = Lr, L2i = Li;
            CSTV(Lr, Li, a3v); float L3r = Lr, L3i = Li;
            float g0r,g0i,g1r,g1i,g2r,g2i,g3r,g3i;
            GC(L3r, L3i, Rr, Ri, a3v, mv.w, g3r, g3i);
            CSTV(Rr, Ri, a2v); GC(L2r, L2i, Rr, Ri, a2v, mv.z, g2r, g2i);
            CSTV(Rr, Ri, a1v); GC(L1r, L1i, Rr, Ri, a1v, mv.y, g1r, g1i);
            CSTV(Rr, Ri, a0v); GC(L0r, L0i, Rr, Ri, a0v, mv.x, g0r, g0i);

            uint4 pk;
            pk.x = (uint)f2h(g0r) | ((uint)f2h(g0i) << 16);
            pk.y = (uint)f2h(g1r) | ((uint)f2h(g1i) << 16);
            pk.z = (uint)f2h(g2r) | ((uint)f2h(g2i) << 16);
            pk.w = (uint)f2h(g3r) | ((uint)f2h(g3i) << 16);
            *reinterpret_cast<uint4*>(&xsp[PCH * tid]) = pk;

            if (e0 >= s && e0 < s + TSEG) {          // own (non-halo) positions
                float4 oa = make_float4(g0r, g0i, g1r, g1i);
                float4 ob = make_float4(g2r, g2i, g3r, g3i);
                size_t off = ((size_t)b * NN + e0) * 2;
                *reinterpret_cast<float4*>(&fs[off])       = oa;
                *reinterpret_cast<float4*>(&fs[off + 4])   = ob;
                *reinterpret_cast<float4*>(&outF[off])     = oa;   // default: fs
                *reinterpret_cast<float4*>(&outF[off + 4]) = ob;
                uint mb = (mv.x > 0.5f ? 1u : 0u) | (mv.y > 0.5f ? 1u : 0u) << 8
                        | (mv.z > 0.5f ? 1u : 0u) << 16 | (mv.w > 0.5f ? 1u : 0u) << 24;
                *reinterpret_cast<uint*>(&mskb[e0 - s]) = mb;
            }
        } else {
            uint4 z = {0u, 0u, 0u, 0u};              // zero 'same' padding
            *reinterpret_cast<uint4*>(&xsp[PCH * tid]) = z;
        }
    } else if (tid >= 320) {
        const int t0 = tid - 320;                    // 192 staging threads
        for (int i = t0; i < 512; i += 192) {
            int co = i >> 4, k = i & 15;
            wt1c[i] = (k < 10) ? f2h(w1[co*10 + (k&1)*5 + (k>>1)]) : (ushort)0;
        }
        for (int i = t0; i < 5120; i += 192) {
            int co = i / 160, k = i % 160;
            wt2c[i] = f2h(w2[co*160 + (k&31)*5 + (k>>5)]);
        }
        for (int i = t0; i < 320; i += 192) {
            int co = i / 160, k = i % 160;
            wt3c[i] = f2h(w3[co*160 + (k&31)*5 + (k>>5)]);
        }
        if (t0 < 32) { b1s[t0] = b1[t0]; b2s[t0] = b2[t0]; if (t0 < 2) b3s[t0] = b3[t0]; }
    }
    __syncthreads();
    // sa (aliased with h1t) is dead from here on.

    const int lane = tid & 63;
    const int wv   = tid >> 6;        // 0..7
    const int cn   = lane & 31;
    const int kh   = lane >> 5;
    const int ml   = lane & 15;       // conv3 16x16: A-row / C-col
    const int kg   = lane >> 4;       // conv3 16x16: k-group 0..3

    // persistent B-fragments (loop-invariant: hoisted out of chunk loop)
    half8 bw1 = ld8(&wt1c[cn * 16 + 8 * kh]);
    half8 bw[10];
    #pragma unroll
    for (int t = 0; t < 10; ++t) bw[t] = ld8(&wt2c[cn*160 + 16*t + 8*kh]);
    half8 bw3[5];
    {
        int co_b = (ml < 2) ? ml : 0;
        #pragma unroll
        for (int q = 0; q < 5; ++q)
            bw3[q] = ld8(&wt3c[co_b*160 + q*32 + kg*8]);
    }

    for (int ch = 0; ch < 4; ++ch) {
        const int cr = ch * CHK;      // chunk base rel s

        // ---- conv1: 9 tiles (rows rel c-4: 0..263); wave0 also does tile 8
        {
            #pragma unroll
            for (int pass = 0; pass < 2; ++pass) {
                int t = (pass == 0) ? wv : ((wv == 0) ? 8 : -1);
                if (t >= 0) {
                    int tb1 = (t < 8) ? 32*t : 232;
                    int x0  = cr + 2 + tb1 + cn;     // xsp idx: (c-s)+2+row+kk
                    union { half8 v8; uint u[4]; } A;
                    if (kh == 0) { A.u[0]=xsp[x0]; A.u[1]=xsp[x0+1];
                                   A.u[2]=xsp[x0+2]; A.u[3]=xsp[x0+3]; }
                    else         { A.u[0]=xsp[x0+4]; A.u[1]=0; A.u[2]=0; A.u[3]=0; }
                    f32x16 a1 = {};
                    a1 = __builtin_amdgcn_mfma_f32_32x32x16_f16(A.v8, bw1, a1, 0, 0, 0);
                    float bias = b1s[cn];
                    #pragma unroll
                    for (int r = 0; r < 16; ++r) {
                        int m = (r&3) + 8*(r>>2) + 4*kh;
                        int row = tb1 + m;
                        int gp  = s + cr - 4 + row;
                        h1t[row*HST + cn] = (gp >= 0 && gp < NN)
                            ? f2h(fmaxf(a1[r] + bias, 0.f)) : (ushort)0;
                    }
                }
            }
        }
        __syncthreads();

        // ---- conv2: 9 tiles; two independent 5-MFMA chains; b128 A-frags ----
        {
            #pragma unroll
            for (int pass = 0; pass < 2; ++pass) {
                int t = (pass == 0) ? wv : ((wv == 0) ? 8 : -1);
                if (t >= 0) {
                    int tb2 = (t < 8) ? 32*t : 228;
                    f32x16 aca = {}, acb = {};
                    #pragma unroll
                    for (int j = 0; j < 5; ++j) {
                        const ushort* rp = &h1t[(tb2 + cn + j)*HST + 8*kh];
                        aca = __builtin_amdgcn_mfma_f32_32x32x16_f16(ld16(rp),      bw[2*j],   aca, 0, 0, 0);
                        acb = __builtin_amdgcn_mfma_f32_32x32x16_f16(ld16(rp + 16), bw[2*j+1], acb, 0, 0, 0);
                    }
                    f32x16 acc = aca + acb;
                    float bias = b2s[cn];
                    #pragma unroll
                    for (int r = 0; r < 16; ++r) {
                        int m = (r&3) + 8*(r>>2) + 4*kh;
                        int row = tb2 + m;
                        int gp  = s + cr - 2 + row;
                        h2t[row*HST + cn] = (gp >= 0 && gp < NN)
                            ? f2h(fmaxf(acc[r] + bias, 0.f)) : (ushort)0;
                    }
                }
            }
        }
        __syncthreads();

        // ---- conv3 via 16x16x32 MFMA (N=2 of 16); 2 tiles/wave; b128 A ----
        {
            #pragma unroll
            for (int t3i = 0; t3i < 2; ++t3i) {
                int rb = 16 * (2*wv + t3i);          // h2t row base
                f32x4 a3 = {};
                #pragma unroll
                for (int q = 0; q < 5; ++q) {
                    half8 av = ld16(&h2t[(rb + ml + q)*HST + kg*8]);
                    a3 = __builtin_amdgcn_mfma_f32_16x16x32_f16(av, bw3[q], a3, 0, 0, 0);
                }
                if (ml < 2) {
                    float bias = b3s[ml];
                    #pragma unroll
                    for (int r = 0; r < 4; ++r) {
                        int p = cr + rb + kg*4 + r;  // rel s
                        if (!mskb[p])
                            outF[((size_t)b*NN + s + p)*2 + ml] = a3[r] + bias;
                    }
                }
            }
        }
        // no barrier needed here: next conv1's post-barrier orders h1t/h2t reuse
    }
}

extern "C" void kernel_launch(void* const* d_in, const int* in_sizes, int n_in,
                              void* d_out, int out_size, void* d_ws, size_t ws_size,
                              hipStream_t stream) {
    const float* v    = (const float*)d_in[0];
    const float* mask = (const float*)d_in[1];
    const float* w1   = (const float*)d_in[2];
    const float* b1   = (const float*)d_in[3];
    const float* w2   = (const float*)d_in[4];
    const float* b2   = (const float*)d_in[5];
    const float* w3   = (const float*)d_in[6];
    const float* b3   = (const float*)d_in[7];

    float* outF = (float*)d_out;                  // feats_final (B,N,2)
    float* fs   = outF + (size_t)BB * NN * 2;     // feats_sparse (B,N,2)

    dim3 g(NN / TSEG, BB);                        // 8 x 64 = 512 blocks
    fused_kernel<<<g, NT, 0, stream>>>(v, mask, w1, b1, w2, b2, w3, b3, outF, fs);
}